// Round 4
// baseline (818.910 us; speedup 1.0000x reference)
//
#include <hip/hip_runtime.h>
#include <hip/hip_cooperative_groups.h>
#include <math.h>

namespace cg = cooperative_groups;

// Shapes: B=32, L=2048, E=512, H=512, V=32000
// Dead code: softmax over singleton axis == 1.0 -> attn_weights == 1/2048 exactly
// -> x/emb/attn_W/attn_b never read; c = relu(mean_L(encoder_out)).
// Mandatory HBM ~420 MB (enc 268 + out_W 131 + GRU W 19) -> ~66 us BW floor.
//
// Primary path: ONE cooperative kernel, 256 blocks x 256 threads (1 block/CU --
// co-residency valid at any VGPR count), 4 grid syncs.
// Fallback path (if hipLaunchCooperativeKernel returns an error, e.g. under
// graph capture): the proven 5-kernel chain from R2. Both paths compute
// identical outputs.
//
// d_out layout (fp32): logp [0,32000) | h_new [32000,64768) | attn_weights [64768,130304)

struct Params {
  const float* h;
  const float* enc;
  const float* Wih_f; const float* Whh_f; const float* bih_f; const float* bhh_f;
  const float* Wih_b; const float* Whh_b; const float* bih_b; const float* bhh_b;
  const float* outW; const float* outb;
  float* out;
  float* partial;  // mega: 32*8*1024 floats
  float* cbuf;     // 32768 floats
  float* logits;   // 32000 floats
};

// ================= PRIMARY: cooperative mega-kernel (256 blocks) =================
__global__ __launch_bounds__(256, 2) void mega(Params p) {
  cg::grid_group grid = cg::this_grid();
  const int tid  = threadIdx.x;
  const int bid  = blockIdx.x;   // 0..255
  const int lane = tid & 63;

  // ---- Phase 1: encoder partial sums. block = (b, ch): 256 rows of 1024 ----
  {
    const int b  = bid >> 3;     // 0..31
    const int ch = bid & 7;      // 0..7
    const float4* src = (const float4*)p.enc + ((size_t)b * 2048 + ch * 256) * 256 + tid;
    float4 acc = make_float4(0.f, 0.f, 0.f, 0.f);
#pragma unroll 8
    for (int l = 0; l < 256; ++l) {
      float4 v = src[(size_t)l * 256];
      acc.x += v.x; acc.y += v.y; acc.z += v.z; acc.w += v.w;
    }
    ((float4*)p.partial)[(size_t)bid * 256 + tid] = acc;
  }
  __threadfence();
  grid.sync();

  // ---- Phase 2: c = relu(mean) (blocks 0..127); attn fill (blocks 128..255, 2 elems/thread) ----
  if (bid < 128) {
    const int idx = bid * 256 + tid;           // 0..32767
    const int b = idx >> 10, d = idx & 1023;
    float s = 0.f;
#pragma unroll
    for (int ch = 0; ch < 8; ++ch) s += p.partial[(size_t)(b * 8 + ch) * 1024 + d];
    s *= (1.0f / 2048.0f);
    p.cbuf[idx] = s > 0.f ? s : 0.f;
  } else {
    const int i = (bid - 128) * 256 + tid;     // 0..32767
    p.out[64768 + i] = 1.0f / 2048.0f;
    p.out[64768 + 32768 + i] = 1.0f / 2048.0f;
  }
  __threadfence();
  grid.sync();

  // ---- Phase 3: bi-GRU. 1024 waves = dir(2) x k(512), 32 batches each ----
  {
    const int w   = bid * 4 + (tid >> 6);      // 0..1023
    const int dir = w >> 9;
    const int k   = w & 511;
    const float* Wih = dir ? p.Wih_b : p.Wih_f;
    const float* Whh = dir ? p.Whh_b : p.Whh_f;
    const float* bih = dir ? p.bih_b : p.bih_f;
    const float* bhh = dir ? p.bhh_b : p.bhh_f;
    const float4* Wih4 = (const float4*)Wih;
    const float4* Whh4 = (const float4*)Whh;

    float4 wr[4], wz[4], wn[4];
#pragma unroll
    for (int i = 0; i < 4; ++i) {
      wr[i] = Wih4[(size_t)k * 256 + i * 64 + lane];
      wz[i] = Wih4[(size_t)(k + 512) * 256 + i * 64 + lane];
      wn[i] = Wih4[(size_t)(k + 1024) * 256 + i * 64 + lane];
    }
    float4 ur[2], uz[2], un[2];
#pragma unroll
    for (int i = 0; i < 2; ++i) {
      ur[i] = Whh4[(size_t)k * 128 + i * 64 + lane];
      uz[i] = Whh4[(size_t)(k + 512) * 128 + i * 64 + lane];
      un[i] = Whh4[(size_t)(k + 1024) * 128 + i * 64 + lane];
    }
    const float bkr = bih[k], bkz = bih[k + 512], bkn = bih[k + 1024];
    const float ckr = bhh[k], ckz = bhh[k + 512], ckn = bhh[k + 1024];

    const float4* c4 = (const float4*)p.cbuf;
    const float4* h4 = (const float4*)p.h + (size_t)dir * 32 * 128;

    for (int b = 0; b < 32; ++b) {
      float pr = 0.f, pz = 0.f, pn = 0.f;
#pragma unroll
      for (int i = 0; i < 4; ++i) {
        float4 v = c4[b * 256 + i * 64 + lane];
        pr += v.x * wr[i].x + v.y * wr[i].y + v.z * wr[i].z + v.w * wr[i].w;
        pz += v.x * wz[i].x + v.y * wz[i].y + v.z * wz[i].z + v.w * wz[i].w;
        pn += v.x * wn[i].x + v.y * wn[i].y + v.z * wn[i].z + v.w * wn[i].w;
      }
      float qr = 0.f, qz = 0.f, qn = 0.f;
#pragma unroll
      for (int i = 0; i < 2; ++i) {
        float4 v = h4[b * 128 + i * 64 + lane];
        qr += v.x * ur[i].x + v.y * ur[i].y + v.z * ur[i].z + v.w * ur[i].w;
        qz += v.x * uz[i].x + v.y * uz[i].y + v.z * uz[i].z + v.w * uz[i].w;
        qn += v.x * un[i].x + v.y * un[i].y + v.z * un[i].z + v.w * un[i].w;
      }
#pragma unroll
      for (int off = 32; off; off >>= 1) {
        pr += __shfl_xor(pr, off, 64);
        pz += __shfl_xor(pz, off, 64);
        pn += __shfl_xor(pn, off, 64);
        qr += __shfl_xor(qr, off, 64);
        qz += __shfl_xor(qz, off, 64);
        qn += __shfl_xor(qn, off, 64);
      }
      if (lane == 0) {
        float r = 1.f / (1.f + expf(-(pr + bkr + qr + ckr)));
        float z = 1.f / (1.f + expf(-(pz + bkz + qz + ckz)));
        float n = tanhf(pn + bkn + r * (qn + ckn));
        float hp = p.h[(size_t)dir * 32 * 512 + (size_t)b * 512 + k];
        p.out[32000 + dir * 16384 + b * 512 + k] = (1.f - z) * n + z * hp;
      }
    }
  }
  __threadfence();
  grid.sync();

  // ---- Phase 4: logits = c_out[31] . out_W[v] + out_b[v], one wave per row ----
  {
    const int w = bid * 4 + (tid >> 6);        // 0..1023
    const float4* hf = (const float4*)(p.out + 32000 + 31 * 512);
    const float4* hb = (const float4*)(p.out + 32000 + 16384 + 31 * 512);
    float4 cv[4];
#pragma unroll
    for (int i = 0; i < 4; ++i) {
      const int pos = i * 64 + lane;
      cv[i] = (pos < 128) ? hf[pos] : hb[pos - 128];
    }
    for (int v = w; v < 32000; v += 1024) {
      const float4* W4 = (const float4*)p.outW + (size_t)v * 256;
      float acc = 0.f;
#pragma unroll
      for (int i = 0; i < 4; ++i) {
        float4 wv = W4[i * 64 + lane];
        acc += cv[i].x * wv.x + cv[i].y * wv.y + cv[i].z * wv.z + cv[i].w * wv.w;
      }
#pragma unroll
      for (int off = 32; off; off >>= 1) acc += __shfl_xor(acc, off, 64);
      if (lane == 0) p.logits[v] = acc + p.outb[v];
    }
  }
  __threadfence();
  grid.sync();

  // ---- Phase 5: block 0 only — logsumexp + logp write (128 KB) ----
  if (bid == 0) {
    __shared__ float red[4];
    const float4* l4 = (const float4*)p.logits;
    float m = -1e30f;
    for (int i = tid; i < 8000; i += 256) {
      float4 v = l4[i];
      m = fmaxf(m, fmaxf(fmaxf(v.x, v.y), fmaxf(v.z, v.w)));
    }
#pragma unroll
    for (int off = 32; off; off >>= 1) m = fmaxf(m, __shfl_xor(m, off, 64));
    if (lane == 0) red[tid >> 6] = m;
    __syncthreads();
    const float gm = fmaxf(fmaxf(red[0], red[1]), fmaxf(red[2], red[3]));
    __syncthreads();
    float s = 0.f;
    for (int i = tid; i < 8000; i += 256) {
      float4 v = l4[i];
      s += expf(v.x - gm) + expf(v.y - gm) + expf(v.z - gm) + expf(v.w - gm);
    }
#pragma unroll
    for (int off = 32; off; off >>= 1) s += __shfl_xor(s, off, 64);
    if (lane == 0) red[tid >> 6] = s;
    __syncthreads();
    const float sub = gm + logf(red[0] + red[1] + red[2] + red[3]);
    float4* o4 = (float4*)p.out;
    for (int i = tid; i < 8000; i += 256) {
      float4 v = l4[i];
      o4[i] = make_float4(v.x - sub, v.y - sub, v.z - sub, v.w - sub);
    }
  }
}

// ================= FALLBACK: proven 5-kernel chain (R2) =================
#define NC 32

__global__ __launch_bounds__(256) void k_enc_partial(const float* __restrict__ enc,
                                                     float* __restrict__ partial) {
  const int tid = threadIdx.x;
  const int ch  = blockIdx.x;
  const int b   = blockIdx.y;
  const int rows = 2048 / NC;
  const float4* src = (const float4*)enc + ((size_t)b * 2048 + (size_t)ch * rows) * 256 + tid;
  float4 acc = make_float4(0.f, 0.f, 0.f, 0.f);
#pragma unroll 8
  for (int l = 0; l < rows; ++l) {
    float4 v = src[(size_t)l * 256];
    acc.x += v.x; acc.y += v.y; acc.z += v.z; acc.w += v.w;
  }
  ((float4*)partial)[((size_t)b * NC + ch) * 256 + tid] = acc;
}

__global__ __launch_bounds__(256) void k_c_fill(const float* __restrict__ partial,
                                                float* __restrict__ c,
                                                float* __restrict__ out) {
  const int bid = blockIdx.x;
  if (bid < 128) {
    const int idx = bid * 256 + threadIdx.x;
    const int b = idx >> 10, d = idx & 1023;
    float s = 0.f;
#pragma unroll
    for (int ch = 0; ch < NC; ++ch) s += partial[((size_t)b * NC + ch) * 1024 + d];
    s *= (1.0f / 2048.0f);
    c[idx] = s > 0.f ? s : 0.f;
  } else {
    const int i = (bid - 128) * 256 + threadIdx.x;
    out[64768 + i] = 1.0f / 2048.0f;
  }
}

__global__ __launch_bounds__(256) void k_gru(
    const float* __restrict__ c, const float* __restrict__ h,
    const float* __restrict__ Wih_f, const float* __restrict__ Whh_f,
    const float* __restrict__ bih_f, const float* __restrict__ bhh_f,
    const float* __restrict__ Wih_b, const float* __restrict__ Whh_b,
    const float* __restrict__ bih_b, const float* __restrict__ bhh_b,
    float* __restrict__ out) {
  const int lane = threadIdx.x & 63;
  const int wid  = (blockIdx.x * 256 + threadIdx.x) >> 6;
  const int dir  = wid >> 9;
  const int k    = wid & 511;
  const float* Wih = dir ? Wih_b : Wih_f;
  const float* Whh = dir ? Whh_b : Whh_f;
  const float* bih = dir ? bih_b : bih_f;
  const float* bhh = dir ? bhh_b : bhh_f;
  const float4* Wih4 = (const float4*)Wih;
  const float4* Whh4 = (const float4*)Whh;

  float4 wr[4], wz[4], wn[4];
#pragma unroll
  for (int i = 0; i < 4; ++i) {
    wr[i] = Wih4[(size_t)k * 256 + i * 64 + lane];
    wz[i] = Wih4[(size_t)(k + 512) * 256 + i * 64 + lane];
    wn[i] = Wih4[(size_t)(k + 1024) * 256 + i * 64 + lane];
  }
  float4 ur[2], uz[2], un[2];
#pragma unroll
  for (int i = 0; i < 2; ++i) {
    ur[i] = Whh4[(size_t)k * 128 + i * 64 + lane];
    uz[i] = Whh4[(size_t)(k + 512) * 128 + i * 64 + lane];
    un[i] = Whh4[(size_t)(k + 1024) * 128 + i * 64 + lane];
  }
  const float bkr = bih[k], bkz = bih[k + 512], bkn = bih[k + 1024];
  const float ckr = bhh[k], ckz = bhh[k + 512], ckn = bhh[k + 1024];

  const float4* c4 = (const float4*)c;
  const float4* h4 = (const float4*)h + (size_t)dir * 32 * 128;

  for (int b = 0; b < 32; ++b) {
    float pr = 0.f, pz = 0.f, pn = 0.f;
#pragma unroll
    for (int i = 0; i < 4; ++i) {
      float4 v = c4[b * 256 + i * 64 + lane];
      pr += v.x * wr[i].x + v.y * wr[i].y + v.z * wr[i].z + v.w * wr[i].w;
      pz += v.x * wz[i].x + v.y * wz[i].y + v.z * wz[i].z + v.w * wz[i].w;
      pn += v.x * wn[i].x + v.y * wn[i].y + v.z * wn[i].z + v.w * wn[i].w;
    }
    float qr = 0.f, qz = 0.f, qn = 0.f;
#pragma unroll
    for (int i = 0; i < 2; ++i) {
      float4 v = h4[b * 128 + i * 64 + lane];
      qr += v.x * ur[i].x + v.y * ur[i].y + v.z * ur[i].z + v.w * ur[i].w;
      qz += v.x * uz[i].x + v.y * uz[i].y + v.z * uz[i].z + v.w * uz[i].w;
      qn += v.x * un[i].x + v.y * un[i].y + v.z * un[i].z + v.w * un[i].w;
    }
#pragma unroll
    for (int off = 32; off; off >>= 1) {
      pr += __shfl_xor(pr, off, 64);
      pz += __shfl_xor(pz, off, 64);
      pn += __shfl_xor(pn, off, 64);
      qr += __shfl_xor(qr, off, 64);
      qz += __shfl_xor(qz, off, 64);
      qn += __shfl_xor(qn, off, 64);
    }
    if (lane == 0) {
      float r = 1.f / (1.f + expf(-(pr + bkr + qr + ckr)));
      float z = 1.f / (1.f + expf(-(pz + bkz + qz + ckz)));
      float n = tanhf(pn + bkn + r * (qn + ckn));
      float hp = h[(size_t)dir * 32 * 512 + (size_t)b * 512 + k];
      out[32000 + dir * 16384 + b * 512 + k] = (1.f - z) * n + z * hp;
    }
  }
}

__global__ __launch_bounds__(256) void k_logits(const float* __restrict__ outW,
                                                const float* __restrict__ outb,
                                                const float* __restrict__ dout,
                                                float* __restrict__ logits) {
  const int lane = threadIdx.x & 63;
  const int v = (blockIdx.x * 256 + threadIdx.x) >> 6;
  const float4* hf = (const float4*)(dout + 32000 + 31 * 512);
  const float4* hb = (const float4*)(dout + 32000 + 16384 + 31 * 512);
  const float4* W4 = (const float4*)outW + (size_t)v * 256;
  float p = 0.f;
#pragma unroll
  for (int i = 0; i < 4; ++i) {
    const int pos = i * 64 + lane;
    float4 cv = (pos < 128) ? hf[pos] : hb[pos - 128];
    float4 wv = W4[pos];
    p += cv.x * wv.x + cv.y * wv.y + cv.z * wv.z + cv.w * wv.w;
  }
#pragma unroll
  for (int off = 32; off; off >>= 1) p += __shfl_xor(p, off, 64);
  if (lane == 0) logits[v] = p + outb[v];
}

__global__ __launch_bounds__(1024) void k_lse_logp(const float* __restrict__ logits,
                                                   float* __restrict__ out) {
  __shared__ float red[16];
  __shared__ float s_m, s_ls;
  const int tid = threadIdx.x, lane = tid & 63, w = tid >> 6;
  float m = -1e30f;
  for (int i = tid; i < 32000; i += 1024) m = fmaxf(m, logits[i]);
#pragma unroll
  for (int off = 32; off; off >>= 1) m = fmaxf(m, __shfl_xor(m, off, 64));
  if (lane == 0) red[w] = m;
  __syncthreads();
  if (tid == 0) {
    float mm = red[0];
    for (int i = 1; i < 16; ++i) mm = fmaxf(mm, red[i]);
    s_m = mm;
  }
  __syncthreads();
  const float gm = s_m;
  float s = 0.f;
  for (int i = tid; i < 32000; i += 1024) s += expf(logits[i] - gm);
#pragma unroll
  for (int off = 32; off; off >>= 1) s += __shfl_xor(s, off, 64);
  if (lane == 0) red[w] = s;
  __syncthreads();
  if (tid == 0) {
    float ss = 0.f;
    for (int i = 0; i < 16; ++i) ss += red[i];
    s_ls = logf(ss);
  }
  __syncthreads();
  const float sub = gm + s_ls;
  for (int i = tid; i < 32000; i += 1024) out[i] = logits[i] - sub;
}

extern "C" void kernel_launch(void* const* d_in, const int* in_sizes, int n_in,
                              void* d_out, int out_size, void* d_ws, size_t ws_size,
                              hipStream_t stream) {
  // 0:x 1:h 2:encoder_out 3:emb 4:attn_W 5:attn_b 6:W_ih_f 7:W_hh_f 8:b_ih_f 9:b_hh_f
  // 10:W_ih_b 11:W_hh_b 12:b_ih_b 13:b_hh_b 14:out_W 15:out_b
  float* ws = (float*)d_ws;
  Params p;
  p.h     = (const float*)d_in[1];
  p.enc   = (const float*)d_in[2];
  p.Wih_f = (const float*)d_in[6];
  p.Whh_f = (const float*)d_in[7];
  p.bih_f = (const float*)d_in[8];
  p.bhh_f = (const float*)d_in[9];
  p.Wih_b = (const float*)d_in[10];
  p.Whh_b = (const float*)d_in[11];
  p.bih_b = (const float*)d_in[12];
  p.bhh_b = (const float*)d_in[13];
  p.outW  = (const float*)d_in[14];
  p.outb  = (const float*)d_in[15];
  p.out   = (float*)d_out;
  // layouts: mega uses 32*8*1024 partial; fallback uses 32*NC*1024. Allocate for the max.
  p.partial = ws;                          // up to 32*32*1024 floats (4 MB)
  p.cbuf    = ws + 32 * 32 * 1024;         // 32768 floats
  p.logits  = p.cbuf + 32768;              // 32000 floats

  void* args[] = { &p };
  hipError_t err = hipLaunchCooperativeKernel(reinterpret_cast<void*>(&mega),
                                              dim3(256), dim3(256), args, 0, stream);
  if (err != hipSuccess) {
    // Deterministic fallback: identical outputs via the proven 5-kernel chain.
    dim3 g1(NC, 32);
    k_enc_partial<<<g1, 256, 0, stream>>>(p.enc, p.partial);
    k_c_fill<<<384, 256, 0, stream>>>(p.partial, p.cbuf, p.out);
    k_gru<<<256, 256, 0, stream>>>(p.cbuf, p.h, p.Wih_f, p.Whh_f, p.bih_f, p.bhh_f,
                                   p.Wih_b, p.Whh_b, p.bih_b, p.bhh_b, p.out);
    k_logits<<<8000, 256, 0, stream>>>(p.outW, p.outb, p.out, p.logits);
    k_lse_logp<<<1, 1024, 0, stream>>>(p.logits, p.out);
  }
}

// Round 5
// 541.082 us; speedup vs baseline: 1.5135x; 1.5135x over previous
//
#include <hip/hip_runtime.h>
#include <math.h>

// Shapes: B=32, L=2048, E=512, H=512, V=32000
// Dead code: softmax over singleton axis == 1.0 -> attn_weights == 1/2048 exactly
// -> x/emb/attn_W/attn_b never read; c = relu(mean_L(encoder_out)).
// Mandatory HBM ~420 MB -> ~66 us BW floor; harness fixed floor ~388 us (poison+restore).
// R4 lesson: grid.sync() costs ~85 us each on 8-XCD MI355X -> multi-kernel chain wins.
//
// d_out layout (fp32): logp [0,32000) | h_new [32000,64768) | attn_weights [64768,130304)

#define NCH 64  // L-chunks for encoder reduction: 64*32 = 2048 blocks (8/CU queued)

// ---------------- K1: partial sums of encoder_out, 32 rows per block ----------------
__global__ __launch_bounds__(256) void k_enc_partial(const float* __restrict__ enc,
                                                     float* __restrict__ partial) {
  const int tid = threadIdx.x;            // one float4 lane-column of the 1024-float row
  const int ch  = blockIdx.x;             // 0..63
  const int b   = blockIdx.y;             // 0..31
  const float4* src = (const float4*)enc + ((size_t)b * 2048 + (size_t)ch * 32) * 256 + tid;
  float4 acc = make_float4(0.f, 0.f, 0.f, 0.f);
#pragma unroll 8
  for (int l = 0; l < 32; ++l) {
    float4 v = src[(size_t)l * 256];
    acc.x += v.x; acc.y += v.y; acc.z += v.z; acc.w += v.w;
  }
  ((float4*)partial)[((size_t)b * NCH + ch) * 256 + tid] = acc;
}

// ---------------- K2: c = relu(mean) (blocks 0..31, float4) + attn fill (blocks 32..95) ----------------
__global__ __launch_bounds__(256) void k_c_fill(const float* __restrict__ partial,
                                                float* __restrict__ c,
                                                float* __restrict__ out) {
  const int bid = blockIdx.x;
  if (bid < 32) {
    const int idx4 = bid * 256 + threadIdx.x;   // 0..8191 float4s of c
    const int b = idx4 >> 8, d4 = idx4 & 255;
    const float4* p4 = (const float4*)partial + (size_t)b * NCH * 256 + d4;
    float4 s = make_float4(0.f, 0.f, 0.f, 0.f);
#pragma unroll 8
    for (int ch = 0; ch < NCH; ++ch) {
      float4 v = p4[(size_t)ch * 256];
      s.x += v.x; s.y += v.y; s.z += v.z; s.w += v.w;
    }
    const float sc = 1.0f / 2048.0f;
    float4 r;
    r.x = s.x > 0.f ? s.x * sc : 0.f;
    r.y = s.y > 0.f ? s.y * sc : 0.f;
    r.z = s.z > 0.f ? s.z * sc : 0.f;
    r.w = s.w > 0.f ? s.w * sc : 0.f;
    ((float4*)c)[idx4] = r;
  } else {
    const int i4 = (bid - 32) * 256 + threadIdx.x;   // 0..16383
    const float w = 1.0f / 2048.0f;
    ((float4*)out)[16192 + i4] = make_float4(w, w, w, w);
  }
}

// ---------------- K3: bi-GRU cells, one wave per (dir, k) ----------------
__global__ __launch_bounds__(256) void k_gru(
    const float* __restrict__ c, const float* __restrict__ h,
    const float* __restrict__ Wih_f, const float* __restrict__ Whh_f,
    const float* __restrict__ bih_f, const float* __restrict__ bhh_f,
    const float* __restrict__ Wih_b, const float* __restrict__ Whh_b,
    const float* __restrict__ bih_b, const float* __restrict__ bhh_b,
    float* __restrict__ out) {
  const int lane = threadIdx.x & 63;
  const int wid  = (blockIdx.x * 256 + threadIdx.x) >> 6;  // 0..1023
  const int dir  = wid >> 9;
  const int k    = wid & 511;
  const float* Wih = dir ? Wih_b : Wih_f;
  const float* Whh = dir ? Whh_b : Whh_f;
  const float* bih = dir ? bih_b : bih_f;
  const float* bhh = dir ? bhh_b : bhh_f;
  const float4* Wih4 = (const float4*)Wih;
  const float4* Whh4 = (const float4*)Whh;

  float4 wr[4], wz[4], wn[4];
#pragma unroll
  for (int i = 0; i < 4; ++i) {
    wr[i] = Wih4[(size_t)k * 256 + i * 64 + lane];
    wz[i] = Wih4[(size_t)(k + 512) * 256 + i * 64 + lane];
    wn[i] = Wih4[(size_t)(k + 1024) * 256 + i * 64 + lane];
  }
  float4 ur[2], uz[2], un[2];
#pragma unroll
  for (int i = 0; i < 2; ++i) {
    ur[i] = Whh4[(size_t)k * 128 + i * 64 + lane];
    uz[i] = Whh4[(size_t)(k + 512) * 128 + i * 64 + lane];
    un[i] = Whh4[(size_t)(k + 1024) * 128 + i * 64 + lane];
  }
  const float bkr = bih[k], bkz = bih[k + 512], bkn = bih[k + 1024];
  const float ckr = bhh[k], ckz = bhh[k + 512], ckn = bhh[k + 1024];

  const float4* c4 = (const float4*)c;
  const float4* h4 = (const float4*)h + (size_t)dir * 32 * 128;

  for (int b = 0; b < 32; ++b) {
    float pr = 0.f, pz = 0.f, pn = 0.f;
#pragma unroll
    for (int i = 0; i < 4; ++i) {
      float4 v = c4[b * 256 + i * 64 + lane];
      pr += v.x * wr[i].x + v.y * wr[i].y + v.z * wr[i].z + v.w * wr[i].w;
      pz += v.x * wz[i].x + v.y * wz[i].y + v.z * wz[i].z + v.w * wz[i].w;
      pn += v.x * wn[i].x + v.y * wn[i].y + v.z * wn[i].z + v.w * wn[i].w;
    }
    float qr = 0.f, qz = 0.f, qn = 0.f;
#pragma unroll
    for (int i = 0; i < 2; ++i) {
      float4 v = h4[b * 128 + i * 64 + lane];
      qr += v.x * ur[i].x + v.y * ur[i].y + v.z * ur[i].z + v.w * ur[i].w;
      qz += v.x * uz[i].x + v.y * uz[i].y + v.z * uz[i].z + v.w * uz[i].w;
      qn += v.x * un[i].x + v.y * un[i].y + v.z * un[i].z + v.w * un[i].w;
    }
#pragma unroll
    for (int off = 32; off; off >>= 1) {
      pr += __shfl_xor(pr, off, 64);
      pz += __shfl_xor(pz, off, 64);
      pn += __shfl_xor(pn, off, 64);
      qr += __shfl_xor(qr, off, 64);
      qz += __shfl_xor(qz, off, 64);
      qn += __shfl_xor(qn, off, 64);
    }
    if (lane == 0) {
      float r = 1.f / (1.f + expf(-(pr + bkr + qr + ckr)));
      float z = 1.f / (1.f + expf(-(pz + bkz + qz + ckz)));
      float n = tanhf(pn + bkn + r * (qn + ckn));
      float hp = h[(size_t)dir * 32 * 512 + (size_t)b * 512 + k];
      out[32000 + dir * 16384 + b * 512 + k] = (1.f - z) * n + z * hp;
    }
  }
}

// ---------------- K4: logits[v] = dot(c_out[31], out_W[v]) + out_b[v] ----------------
__global__ __launch_bounds__(256) void k_logits(const float* __restrict__ outW,
                                                const float* __restrict__ outb,
                                                const float* __restrict__ dout,
                                                float* __restrict__ logits) {
  const int lane = threadIdx.x & 63;
  const int v = (blockIdx.x * 256 + threadIdx.x) >> 6;  // 0..31999
  const float4* hf = (const float4*)(dout + 32000 + 31 * 512);
  const float4* hb = (const float4*)(dout + 32000 + 16384 + 31 * 512);
  const float4* W4 = (const float4*)outW + (size_t)v * 256;
  float p = 0.f;
#pragma unroll
  for (int i = 0; i < 4; ++i) {
    const int pos = i * 64 + lane;
    float4 cv = (pos < 128) ? hf[pos] : hb[pos - 128];
    float4 wv = W4[pos];
    p += cv.x * wv.x + cv.y * wv.y + cv.z * wv.z + cv.w * wv.w;
  }
#pragma unroll
  for (int off = 32; off; off >>= 1) p += __shfl_xor(p, off, 64);
  if (lane == 0) logits[v] = p + outb[v];
}

// ---------------- K5: fused logsumexp + logp (single block, float4, L2-hot) ----------------
__global__ __launch_bounds__(1024) void k_lse_logp(const float* __restrict__ logits,
                                                   float* __restrict__ out) {
  __shared__ float red[16];
  __shared__ float s_m, s_ls;
  const int tid = threadIdx.x, lane = tid & 63, w = tid >> 6;
  const float4* l4 = (const float4*)logits;
  float m = -1e30f;
  for (int i = tid; i < 8000; i += 1024) {
    float4 v = l4[i];
    m = fmaxf(m, fmaxf(fmaxf(v.x, v.y), fmaxf(v.z, v.w)));
  }
#pragma unroll
  for (int off = 32; off; off >>= 1) m = fmaxf(m, __shfl_xor(m, off, 64));
  if (lane == 0) red[w] = m;
  __syncthreads();
  if (tid == 0) {
    float mm = red[0];
    for (int i = 1; i < 16; ++i) mm = fmaxf(mm, red[i]);
    s_m = mm;
  }
  __syncthreads();
  const float gm = s_m;
  float s = 0.f;
  for (int i = tid; i < 8000; i += 1024) {
    float4 v = l4[i];
    s += expf(v.x - gm) + expf(v.y - gm) + expf(v.z - gm) + expf(v.w - gm);
  }
#pragma unroll
  for (int off = 32; off; off >>= 1) s += __shfl_xor(s, off, 64);
  if (lane == 0) red[w] = s;
  __syncthreads();
  if (tid == 0) {
    float ss = 0.f;
    for (int i = 0; i < 16; ++i) ss += red[i];
    s_ls = logf(ss);
  }
  __syncthreads();
  const float sub = gm + s_ls;
  float4* o4 = (float4*)out;
  for (int i = tid; i < 8000; i += 1024) {
    float4 v = l4[i];
    o4[i] = make_float4(v.x - sub, v.y - sub, v.z - sub, v.w - sub);
  }
}

extern "C" void kernel_launch(void* const* d_in, const int* in_sizes, int n_in,
                              void* d_out, int out_size, void* d_ws, size_t ws_size,
                              hipStream_t stream) {
  // 0:x 1:h 2:encoder_out 3:emb 4:attn_W 5:attn_b 6:W_ih_f 7:W_hh_f 8:b_ih_f 9:b_hh_f
  // 10:W_ih_b 11:W_hh_b 12:b_ih_b 13:b_hh_b 14:out_W 15:out_b
  const float* h     = (const float*)d_in[1];
  const float* enc   = (const float*)d_in[2];
  const float* Wih_f = (const float*)d_in[6];
  const float* Whh_f = (const float*)d_in[7];
  const float* bih_f = (const float*)d_in[8];
  const float* bhh_f = (const float*)d_in[9];
  const float* Wih_b = (const float*)d_in[10];
  const float* Whh_b = (const float*)d_in[11];
  const float* bih_b = (const float*)d_in[12];
  const float* bhh_b = (const float*)d_in[13];
  const float* outW  = (const float*)d_in[14];
  const float* outb  = (const float*)d_in[15];
  float* out = (float*)d_out;
  float* ws  = (float*)d_ws;

  float* partial = ws;                          // 32*NCH*1024 floats (8 MB)
  float* cbuf    = partial + 32 * NCH * 1024;   // 32768 floats
  float* logits  = cbuf + 32768;                // 32000 floats

  dim3 g1(NCH, 32);
  k_enc_partial<<<g1, 256, 0, stream>>>(enc, partial);
  k_c_fill<<<96, 256, 0, stream>>>(partial, cbuf, out);
  k_gru<<<256, 256, 0, stream>>>(cbuf, h, Wih_f, Whh_f, bih_f, bhh_f,
                                 Wih_b, Whh_b, bih_b, bhh_b, out);
  k_logits<<<8000, 256, 0, stream>>>(outW, outb, out, logits);
  k_lse_logp<<<1, 1024, 0, stream>>>(logits, out);
}